// Round 6
// baseline (243.277 us; speedup 1.0000x reference)
//
#include <hip/hip_runtime.h>
#include <hip/hip_bf16.h>

// Problem constants (from reference)
#define LL 2000
#define MM 3
#define FF 512
#define NN (MM * LL)          // 6000 nodes
#define CAP 128               // bucket capacity; deg ~ N(66.7, 8.2) -> P(any>128) ~ 1e-9

typedef __attribute__((ext_vector_type(8))) short bf16x8;
typedef __attribute__((ext_vector_type(4))) float f32x4;

__device__ __forceinline__ unsigned short f2bf(float x) {
    __hip_bfloat16 b = __float2bfloat16(x);
    return *(unsigned short*)&b;
}

// async global->LDS, 16B per lane. lds dest is wave-uniform base + lane*16.
__device__ __forceinline__ void gload16(const void* gsrc, void* ldst) {
    __builtin_amdgcn_global_load_lds((const __attribute__((address_space(1))) unsigned int*)gsrc,
                                     (__attribute__((address_space(3))) unsigned int*)ldst,
                                     16, 0, 0);
}

// ---------------------------------------------------------------------------
// Fused prep: block-range dispatch.  (EXACT r0-baseline form.)
//  [0, 3000):     concat [x_a;x_v;x_t] -> feat bf16, out fp32 init
//  [3000, 3256):  weight transpose+cvt, slots: 0=gW0^T 1=fW0^T 2=gW1^T 3=fW1^T
//  [3256, ...):   edge histogram: pir[e] = rank of edge e within its row
//  NOTE: int-only atomics; NO fp32 rowsum atomics (r1/r2: ~25-30us TCC tax).
// ---------------------------------------------------------------------------
__global__ __launch_bounds__(256) void prep(const float* __restrict__ xa,
                                            const float* __restrict__ xv,
                                            const float* __restrict__ xt,
                                            unsigned short* __restrict__ feat,
                                            float* __restrict__ out_sum,
                                            const float* __restrict__ gcnW,
                                            const float* __restrict__ fcW,
                                            unsigned short* __restrict__ Wt,
                                            const int* __restrict__ esrc,
                                            int* __restrict__ counts,
                                            int* __restrict__ pir, int E) {
    __shared__ unsigned short tile[64][65];
    int b = blockIdx.x;
    int tid = threadIdx.x;
    if (b < 3000) {
        // ----- concat -----
        int idx4 = b * 256 + tid;
        const int per4 = (LL * FF) / 4;
        const float4* src;
        int off;
        if (idx4 < per4)            { src = (const float4*)xa; off = idx4; }
        else if (idx4 < 2 * per4)   { src = (const float4*)xv; off = idx4 - per4; }
        else                        { src = (const float4*)xt; off = idx4 - 2 * per4; }
        float4 v = src[off];
        ((float4*)out_sum)[idx4] = v;
        ushort4 pk;
        pk.x = f2bf(v.x); pk.y = f2bf(v.y); pk.z = f2bf(v.z); pk.w = f2bf(v.w);
        ((ushort4*)feat)[idx4] = pk;
    } else if (b < 3256) {
        // ----- wtrans -----
        int idx = b - 3000;
        int mz = idx >> 6;          // 0,1 gcn ; 2,3 fc
        int rem = idx & 63;
        int k0 = (rem >> 3) * 64;
        int n0 = (rem & 7) * 64;
        int layer = (mz < 2) ? mz : mz - 2;
        const float* src = (mz < 2) ? (gcnW + (size_t)layer * FF * FF)
                                    : (fcW + (size_t)layer * FF * FF);
        int slot = (mz < 2) ? (mz * 2) : ((mz - 2) * 2 + 1);
        unsigned short* dst = Wt + (size_t)slot * FF * FF;
        for (int i = tid; i < 64 * 64; i += 256) {
            int r = i >> 6, c = i & 63;
            tile[r][c] = f2bf(src[(size_t)(k0 + r) * FF + n0 + c]);
        }
        __syncthreads();
        for (int i = tid; i < 64 * 64; i += 256) {
            int r = i >> 6, c = i & 63;
            dst[(size_t)(n0 + r) * FF + k0 + c] = tile[c][r];
        }
    } else {
        // ----- edge histogram -----
        int e = (b - 3256) * 256 + tid;
        if (e < E) pir[e] = atomicAdd(&counts[esrc[e]], 1);
    }
}

// ---------------------------------------------------------------------------
// 128x128 MFMA GEMM core (guide-verified tile ladder: 64^2=343TF -> 128^2=912TF).
// 256 threads = 4 waves in 2x2; each wave owns 64x64 = 4x4 frags of 16x16.
// BK=64, LDS 2x16KB, XOR-swizzled chunks (same algebra as the 64^2 version),
// gload16 width-16 staging with per-wave linear LDS dest.
// ---------------------------------------------------------------------------
#define BM 128

// ---------------------------------------------------------------------------
// Merged dispatch: scatter blocks [0, sblk) + gemm0 blocks [sblk, ...).
// Scatter first: long-latency random stores start earliest, hide under MFMA.
// scatter (atomic-free, 4B packed): bucket[r*CAP + pir[e]] = bf16(w)<<16 | col
// gemm0: H = feat @ gW0 (128x128 tile, store bf16).
// ---------------------------------------------------------------------------
__global__ __launch_bounds__(256) void gemm0_scatter(const unsigned short* __restrict__ A,
                                                     const unsigned short* __restrict__ Bt,
                                                     unsigned short* __restrict__ Hout,
                                                     int M, int gxm, int sblk,
                                                     const int* __restrict__ esrc,
                                                     const int* __restrict__ edst,
                                                     const float* __restrict__ ew,
                                                     const int* __restrict__ pir,
                                                     unsigned int* __restrict__ bucket, int E) {
    __shared__ short As[BM * 64];
    __shared__ short Bs[BM * 64];
    int b = blockIdx.x;
    int tid = threadIdx.x;
    if (b < sblk) {
        // ----- scatter -----
        int e = b * 256 + tid;
        if (e < E) {
            int r = esrc[e];
            int slot = pir[e];
            if (slot < CAP)
                bucket[(size_t)r * CAP + slot] =
                    ((unsigned int)f2bf(ew[e]) << 16) | (unsigned int)edst[e];
        }
        return;
    }
    // ----- gemm0: 128x128 tile -----
    int bg = b - sblk;
    int wave = tid >> 6;
    int lane = tid & 63;
    int lane16 = lane & 15;
    int quad = lane >> 4;
    int m0 = (bg % gxm) * BM;
    int n0 = (bg / gxm) * BM;
    int wm = (wave >> 1) * 64;
    int wn = (wave & 1) * 64;

    f32x4 acc[4][4] = {};

    for (int k0 = 0; k0 < FF; k0 += 64) {
#pragma unroll
        for (int s = 0; s < 4; s++) {
            int c = s * 256 + wave * 64 + lane;   // chunk id, 8 bf16 = 16B each
            int row = c >> 3;                     // 0..127
            int kc = (c & 7) ^ (row & 7);
            int ar = m0 + row; if (ar >= M) ar = M - 1;
            gload16((const short*)A + (size_t)ar * FF + k0 + kc * 8,
                    &As[(s * 256 + wave * 64) * 8]);
            gload16((const short*)Bt + (size_t)(n0 + row) * FF + k0 + kc * 8,
                    &Bs[(s * 256 + wave * 64) * 8]);
        }
        __syncthreads();
#pragma unroll
        for (int kk = 0; kk < 2; kk++) {
            bf16x8 a[4], bb[4];
#pragma unroll
            for (int mt = 0; mt < 4; mt++) {
                int row = wm + mt * 16 + lane16;
                int kc = (kk * 4 + quad) ^ (row & 7);
                a[mt] = *(const bf16x8*)&As[row * 64 + kc * 8];
            }
#pragma unroll
            for (int nt = 0; nt < 4; nt++) {
                int row = wn + nt * 16 + lane16;
                int kc = (kk * 4 + quad) ^ (row & 7);
                bb[nt] = *(const bf16x8*)&Bs[row * 64 + kc * 8];
            }
#pragma unroll
            for (int mt = 0; mt < 4; mt++)
#pragma unroll
                for (int nt = 0; nt < 4; nt++)
                    acc[mt][nt] = __builtin_amdgcn_mfma_f32_16x16x32_bf16(a[mt], bb[nt], acc[mt][nt], 0, 0, 0);
        }
        __syncthreads();
    }

#pragma unroll
    for (int mt = 0; mt < 4; mt++) {
#pragma unroll
        for (int nt = 0; nt < 4; nt++) {
            int n = n0 + wn + nt * 16 + lane16;
#pragma unroll
            for (int rr = 0; rr < 4; rr++) {
                int m = m0 + wm + mt * 16 + quad * 4 + rr;
                if (m < M) Hout[(size_t)m * FF + n] = f2bf(acc[mt][nt][rr]);
            }
        }
    }
}

// ---------------------------------------------------------------------------
// Row sums over packed buckets -> dinv. One wave per row, 4 rows/block.
// (EXACT r0-baseline form.)
// ---------------------------------------------------------------------------
__global__ __launch_bounds__(256) void rowsum_dinv(const unsigned int* __restrict__ bucket,
                                                   const int* __restrict__ counts,
                                                   float* __restrict__ dinv) {
    int wave = threadIdx.x >> 6, lane = threadIdx.x & 63;
    int r = blockIdx.x * 4 + wave;
    int s = r * CAP;
    int e = s + min(counts[r], CAP);
    float sum = 0.0f;
    for (int i = s + lane; i < e; i += 64)
        sum += __uint_as_float(bucket[i] & 0xFFFF0000u);
#pragma unroll
    for (int off = 32; off > 0; off >>= 1) sum += __shfl_xor(sum, off);
    if (lane == 0) dinv[r] = (sum > 0.0f) ? rsqrtf(sum) : 0.0f;
}

// ---------------------------------------------------------------------------
// SpMM gather over packed buckets. (EXACT r0-baseline form — measured near
// its per-CU miss-processing floor; partitioning/pipelining all regressed.)
//   feat[r,:] = relu( dinv[r] * sum_e (w_e*dinv[c_e]) * H[c_e,:] + bias )
// ---------------------------------------------------------------------------
__device__ __forceinline__ void accum8(float* acc, uint4 h, float v) {
    unsigned int d[4] = {h.x, h.y, h.z, h.w};
#pragma unroll
    for (int k = 0; k < 4; k++) {
        float lo = __uint_as_float(d[k] << 16);
        float hi = __uint_as_float(d[k] & 0xFFFF0000u);
        acc[2 * k]     = fmaf(v, lo, acc[2 * k]);
        acc[2 * k + 1] = fmaf(v, hi, acc[2 * k + 1]);
    }
}

__global__ __launch_bounds__(256) void spmm_bias_relu(const unsigned short* __restrict__ H,
                                                      const int* __restrict__ counts,
                                                      const unsigned int* __restrict__ bucket,
                                                      const float* __restrict__ dinv,
                                                      const float* __restrict__ bias,
                                                      unsigned short* __restrict__ featOut) {
    int wave = threadIdx.x >> 6, lane = threadIdx.x & 63;
    int r = blockIdx.x * 4 + wave;
    int s = r * CAP;
    int e = s + min(counts[r], CAP);
    int f0 = lane * 8;
    const unsigned short* Hf = H + f0;
    float acc[8] = {0, 0, 0, 0, 0, 0, 0, 0};

    int i = s;
    uint4 pk;
    bool have = (i + 4 <= e);
    if (have) pk = *(const uint4*)&bucket[i];
    while (have) {
        unsigned int q0 = pk.x, q1 = pk.y, q2 = pk.z, q3 = pk.w;
        uint4 a0 = *(const uint4*)(Hf + (size_t)(q0 & 0xFFFF) * FF);
        uint4 a1 = *(const uint4*)(Hf + (size_t)(q1 & 0xFFFF) * FF);
        uint4 a2 = *(const uint4*)(Hf + (size_t)(q2 & 0xFFFF) * FF);
        uint4 a3 = *(const uint4*)(Hf + (size_t)(q3 & 0xFFFF) * FF);
        float v0 = __uint_as_float(q0 & 0xFFFF0000u) * dinv[q0 & 0xFFFF];
        float v1 = __uint_as_float(q1 & 0xFFFF0000u) * dinv[q1 & 0xFFFF];
        float v2 = __uint_as_float(q2 & 0xFFFF0000u) * dinv[q2 & 0xFFFF];
        float v3 = __uint_as_float(q3 & 0xFFFF0000u) * dinv[q3 & 0xFFFF];
        i += 4;
        have = (i + 4 <= e);
        if (have) pk = *(const uint4*)&bucket[i];
        accum8(acc, a0, v0);
        accum8(acc, a1, v1);
        accum8(acc, a2, v2);
        accum8(acc, a3, v3);
    }
    for (; i < e; i++) {
        unsigned int q = bucket[i];
        uint4 a = *(const uint4*)(Hf + (size_t)(q & 0xFFFF) * FF);
        accum8(acc, a, __uint_as_float(q & 0xFFFF0000u) * dinv[q & 0xFFFF]);
    }

    float dr = dinv[r];
    float4 b0 = *(const float4*)(bias + f0);
    float4 b1 = *(const float4*)(bias + f0 + 4);
    float bb[8] = {b0.x, b0.y, b0.z, b0.w, b1.x, b1.y, b1.z, b1.w};
    unsigned int o[4];
#pragma unroll
    for (int k = 0; k < 4; k++) {
        float v0 = fmaxf(fmaf(acc[2 * k], dr, bb[2 * k]), 0.0f);
        float v1 = fmaxf(fmaf(acc[2 * k + 1], dr, bb[2 * k + 1]), 0.0f);
        o[k] = (unsigned int)f2bf(v0) | ((unsigned int)f2bf(v1) << 16);
    }
    uint4 ov; ov.x = o[0]; ov.y = o[1]; ov.z = o[2]; ov.w = o[3];
    *(uint4*)(featOut + (size_t)r * FF + f0) = ov;
}

// ---------------------------------------------------------------------------
// MFMA GEMM over stacked transposed weights Bt[n][k]. 128x128 tile, BK=64,
// 256 threads = 4 waves (2x2 of 64x64), XOR-swizzled LDS.
// MODE 1: all cols -> out += leaky_relu(v + fbias[n]), grid.y = 4
// MODE 2: n0<512 -> out += leaky_relu(v + fbias[n]); n0>=512 -> H store at
//         n-512, grid.y = 8 (Bt = [fW_i^T ; gW_{i+1}^T], same input feat)
// ---------------------------------------------------------------------------
template <int MODE>
__global__ __launch_bounds__(256) void gemm_bf16(const unsigned short* __restrict__ A,
                                                 const unsigned short* __restrict__ Bt,
                                                 const float* __restrict__ fbias,
                                                 unsigned short* __restrict__ Hout,
                                                 float* __restrict__ out,
                                                 int M) {
    __shared__ short As[BM * 64];
    __shared__ short Bs[BM * 64];
    int tid = threadIdx.x;
    int wave = tid >> 6;
    int lane = tid & 63;
    int lane16 = lane & 15;
    int quad = lane >> 4;
    int m0 = blockIdx.x * BM;
    int n0 = blockIdx.y * BM;
    int wm = (wave >> 1) * 64;
    int wn = (wave & 1) * 64;

    f32x4 acc[4][4] = {};

    for (int k0 = 0; k0 < FF; k0 += 64) {
#pragma unroll
        for (int s = 0; s < 4; s++) {
            int c = s * 256 + wave * 64 + lane;
            int row = c >> 3;
            int kc = (c & 7) ^ (row & 7);
            int ar = m0 + row; if (ar >= M) ar = M - 1;
            gload16((const short*)A + (size_t)ar * FF + k0 + kc * 8,
                    &As[(s * 256 + wave * 64) * 8]);
            gload16((const short*)Bt + (size_t)(n0 + row) * FF + k0 + kc * 8,
                    &Bs[(s * 256 + wave * 64) * 8]);
        }
        __syncthreads();
#pragma unroll
        for (int kk = 0; kk < 2; kk++) {
            bf16x8 a[4], bb[4];
#pragma unroll
            for (int mt = 0; mt < 4; mt++) {
                int row = wm + mt * 16 + lane16;
                int kc = (kk * 4 + quad) ^ (row & 7);
                a[mt] = *(const bf16x8*)&As[row * 64 + kc * 8];
            }
#pragma unroll
            for (int nt = 0; nt < 4; nt++) {
                int row = wn + nt * 16 + lane16;
                int kc = (kk * 4 + quad) ^ (row & 7);
                bb[nt] = *(const bf16x8*)&Bs[row * 64 + kc * 8];
            }
#pragma unroll
            for (int mt = 0; mt < 4; mt++)
#pragma unroll
                for (int nt = 0; nt < 4; nt++)
                    acc[mt][nt] = __builtin_amdgcn_mfma_f32_16x16x32_bf16(a[mt], bb[nt], acc[mt][nt], 0, 0, 0);
        }
        __syncthreads();
    }

    bool isFc = (MODE == 1) || (MODE == 2 && n0 < FF);
#pragma unroll
    for (int mt = 0; mt < 4; mt++) {
#pragma unroll
        for (int nt = 0; nt < 4; nt++) {
            int n = n0 + wn + nt * 16 + lane16;
            float bv = isFc ? fbias[n] : 0.0f;
#pragma unroll
            for (int rr = 0; rr < 4; rr++) {
                int m = m0 + wm + mt * 16 + quad * 4 + rr;
                if (m < M) {
                    float v = acc[mt][nt][rr];
                    if (isFc) {
                        v += bv;
                        v = (v > 0.0f) ? v : 0.01f * v;
                        out[(size_t)m * FF + n] += v;
                    } else {
                        Hout[(size_t)m * FF + (n - FF)] = f2bf(v);
                    }
                }
            }
        }
    }
}

// ---------------------------------------------------------------------------
extern "C" void kernel_launch(void* const* d_in, const int* in_sizes, int n_in,
                              void* d_out, int out_size, void* d_ws, size_t ws_size,
                              hipStream_t stream) {
    const float* xa      = (const float*)d_in[0];
    const float* xv      = (const float*)d_in[1];
    const float* xt      = (const float*)d_in[2];
    const float* ew      = (const float*)d_in[3];
    const float* gcn_W   = (const float*)d_in[4];
    const float* gcn_b   = (const float*)d_in[5];
    const float* fc_W    = (const float*)d_in[6];
    const float* fc_b    = (const float*)d_in[7];
    const int*   eidx    = (const int*)d_in[8];
    const int E = in_sizes[8] / 2;
    const int* esrc = eidx;
    const int* edst = eidx + E;

    float* out = (float*)d_out;

    // workspace layout (64B aligned blocks) — EXACT r0 baseline
    char* w = (char*)d_ws;
    int*          counts = (int*)         (w + 0);          // 24,000 (pad 24,064)
    float*        dinv   = (float*)       (w + 24064);      // 24,000 (pad 48,128)
    unsigned int* bucket = (unsigned int*)(w + 48128);      // 6000*128*4 = 3,072,000
    unsigned short* feat = (unsigned short*)(w + 3120128);  // 6,144,000
    unsigned short* H    = (unsigned short*)(w + 9264128);  // 6,144,000
    unsigned short* Wt   = (unsigned short*)(w + 15408128); // 2,097,152
    int*          pir    = (int*)         (w + 17505280);   // E*4 = 1,600,000

    hipMemsetAsync(counts, 0, 24000, stream);

    const int eblocks = (E + 255) / 256;
    prep<<<3256 + eblocks, 256, 0, stream>>>(xa, xv, xt, feat, out,
                                             gcn_W, fc_W, Wt, esrc, counts, pir, E);

    const int gxm = (NN + BM - 1) / BM;   // 47 (128-row tiles)
    const int ngemm0 = gxm * (FF / BM);   // 47*4 = 188
    // Wt slots: 0=gW0^T, 1=fW0^T, 2=gW1^T, 3=fW1^T (slots 1,2 contiguous)
    // merged: scatter (first, starts early) || H0 = feat0 @ gW0
    gemm0_scatter<<<eblocks + ngemm0, 256, 0, stream>>>(feat, Wt, H, NN, gxm, eblocks,
                                                        esrc, edst, ew, pir, bucket, E);
    rowsum_dinv<<<NN / 4, 256, 0, stream>>>(bucket, counts, dinv);

    // feat1 = relu(gcn@H0 + gb0)
    spmm_bias_relu<<<NN / 4, 256, 0, stream>>>(H, counts, bucket, dinv, gcn_b, feat);
    // out += leaky(feat1@fW0 + fb0)  AND  H1 = feat1 @ gW1   (fused)
    gemm_bf16<2><<<dim3(gxm, 8), 256, 0, stream>>>(feat, Wt + (size_t)FF * FF, fc_b, H, out, NN);
    // feat2 = relu(gcn@H1 + gb1)
    spmm_bias_relu<<<NN / 4, 256, 0, stream>>>(H, counts, bucket, dinv, gcn_b + FF, feat);
    // out += leaky(feat2@fW1 + fb1)
    gemm_bf16<1><<<dim3(gxm, 4), 256, 0, stream>>>(feat, Wt + (size_t)3 * FF * FF, fc_b + FF, nullptr, out, NN);
}

// Round 7
// 210.692 us; speedup vs baseline: 1.1547x; 1.1547x over previous
//
#include <hip/hip_runtime.h>
#include <hip/hip_bf16.h>

// Problem constants (from reference)
#define LL 2000
#define MM 3
#define FF 512
#define NN (MM * LL)          // 6000 nodes
#define CAP 128               // bucket capacity; deg ~ N(66.7, 8.2) -> P(any>128) ~ 1e-9

typedef __attribute__((ext_vector_type(8))) short bf16x8;
typedef __attribute__((ext_vector_type(4))) float f32x4;

__device__ __forceinline__ unsigned short f2bf(float x) {
    __hip_bfloat16 b = __float2bfloat16(x);
    return *(unsigned short*)&b;
}

// async global->LDS, 16B per lane. lds dest is wave-uniform base + lane*16.
__device__ __forceinline__ void gload16(const void* gsrc, void* ldst) {
    __builtin_amdgcn_global_load_lds((const __attribute__((address_space(1))) unsigned int*)gsrc,
                                     (__attribute__((address_space(3))) unsigned int*)ldst,
                                     16, 0, 0);
}

// ---------------------------------------------------------------------------
// Fused prep: block-range dispatch.
//  [0, 3000):     concat [x_a;x_v;x_t] -> feat bf16, out fp32 init
//  [3000, 3256):  weight transpose+cvt, slots: 0=gW0^T 1=fW0^T 2=gW1^T 3=fW1^T
//  [3256, ...):   edge histogram: pir[e] = rank of edge e within its row
//  Verified-optimal notes (r1-r6 attacks all regressed):
//   - int-only atomics; fp32 rowsum atomics cost ~25-30us (r1/r2)
//   - scatter must NOT live here (streaming kernel can't hide it, r1)
// ---------------------------------------------------------------------------
__global__ __launch_bounds__(256) void prep(const float* __restrict__ xa,
                                            const float* __restrict__ xv,
                                            const float* __restrict__ xt,
                                            unsigned short* __restrict__ feat,
                                            float* __restrict__ out_sum,
                                            const float* __restrict__ gcnW,
                                            const float* __restrict__ fcW,
                                            unsigned short* __restrict__ Wt,
                                            const int* __restrict__ esrc,
                                            int* __restrict__ counts,
                                            int* __restrict__ pir, int E) {
    __shared__ unsigned short tile[64][65];
    int b = blockIdx.x;
    int tid = threadIdx.x;
    if (b < 3000) {
        // ----- concat -----
        int idx4 = b * 256 + tid;
        const int per4 = (LL * FF) / 4;
        const float4* src;
        int off;
        if (idx4 < per4)            { src = (const float4*)xa; off = idx4; }
        else if (idx4 < 2 * per4)   { src = (const float4*)xv; off = idx4 - per4; }
        else                        { src = (const float4*)xt; off = idx4 - 2 * per4; }
        float4 v = src[off];
        ((float4*)out_sum)[idx4] = v;
        ushort4 pk;
        pk.x = f2bf(v.x); pk.y = f2bf(v.y); pk.z = f2bf(v.z); pk.w = f2bf(v.w);
        ((ushort4*)feat)[idx4] = pk;
    } else if (b < 3256) {
        // ----- wtrans -----
        int idx = b - 3000;
        int mz = idx >> 6;          // 0,1 gcn ; 2,3 fc
        int rem = idx & 63;
        int k0 = (rem >> 3) * 64;
        int n0 = (rem & 7) * 64;
        int layer = (mz < 2) ? mz : mz - 2;
        const float* src = (mz < 2) ? (gcnW + (size_t)layer * FF * FF)
                                    : (fcW + (size_t)layer * FF * FF);
        int slot = (mz < 2) ? (mz * 2) : ((mz - 2) * 2 + 1);
        unsigned short* dst = Wt + (size_t)slot * FF * FF;
        for (int i = tid; i < 64 * 64; i += 256) {
            int r = i >> 6, c = i & 63;
            tile[r][c] = f2bf(src[(size_t)(k0 + r) * FF + n0 + c]);
        }
        __syncthreads();
        for (int i = tid; i < 64 * 64; i += 256) {
            int r = i >> 6, c = i & 63;
            dst[(size_t)(n0 + r) * FF + k0 + c] = tile[c][r];
        }
    } else {
        // ----- edge histogram -----
        int e = (b - 3256) * 256 + tid;
        if (e < E) pir[e] = atomicAdd(&counts[esrc[e]], 1);
    }
}

// ---------------------------------------------------------------------------
// Merged dispatch: scatter blocks [0, sblk) + gemm0 blocks [sblk, ...).
// Scatter first: long-latency random stores start earliest, hide under MFMA.
// scatter (atomic-free, 4B packed): bucket[r*CAP + pir[e]] = bf16(w)<<16 | col
// gemm0: H = feat @ gW0 (64x64 tile, store bf16).
// 64x64 tile is verified optimal at these shapes: 128^2 (r6) starves the
// grid (188-376 wg on 256 CUs) and regressed +33us.
// ---------------------------------------------------------------------------
__global__ __launch_bounds__(256) void gemm0_scatter(const unsigned short* __restrict__ A,
                                                     const unsigned short* __restrict__ Bt,
                                                     unsigned short* __restrict__ Hout,
                                                     int M, int gxm, int sblk,
                                                     const int* __restrict__ esrc,
                                                     const int* __restrict__ edst,
                                                     const float* __restrict__ ew,
                                                     const int* __restrict__ pir,
                                                     unsigned int* __restrict__ bucket, int E) {
    __shared__ short As[64 * 64];
    __shared__ short Bs[64 * 64];
    int b = blockIdx.x;
    int tid = threadIdx.x;
    if (b < sblk) {
        // ----- scatter -----
        int e = b * 256 + tid;
        if (e < E) {
            int r = esrc[e];
            int slot = pir[e];
            if (slot < CAP)
                bucket[(size_t)r * CAP + slot] =
                    ((unsigned int)f2bf(ew[e]) << 16) | (unsigned int)edst[e];
        }
        return;
    }
    // ----- gemm0 -----
    int bg = b - sblk;
    int wave = tid >> 6;
    int lane = tid & 63;
    int lane16 = lane & 15;
    int quad = lane >> 4;
    int m0 = (bg % gxm) * 64;
    int n0 = (bg / gxm) * 64;
    int wm = (wave >> 1) * 32;
    int wn = (wave & 1) * 32;

    f32x4 acc[2][2] = {};

    for (int k0 = 0; k0 < FF; k0 += 64) {
#pragma unroll
        for (int s = 0; s < 2; s++) {
            int c = wave * 128 + s * 64 + lane;
            int row = c >> 3;
            int kc = (c & 7) ^ (row & 7);
            int ar = m0 + row; if (ar >= M) ar = M - 1;
            gload16((const short*)A + (size_t)ar * FF + k0 + kc * 8,
                    &As[(wave * 128 + s * 64) * 8]);
            gload16((const short*)Bt + (size_t)(n0 + row) * FF + k0 + kc * 8,
                    &Bs[(wave * 128 + s * 64) * 8]);
        }
        __syncthreads();
#pragma unroll
        for (int kk = 0; kk < 2; kk++) {
            bf16x8 a[2], bb[2];
#pragma unroll
            for (int mt = 0; mt < 2; mt++) {
                int row = wm + mt * 16 + lane16;
                int kc = (kk * 4 + quad) ^ (row & 7);
                a[mt] = *(const bf16x8*)&As[row * 64 + kc * 8];
            }
#pragma unroll
            for (int nt = 0; nt < 2; nt++) {
                int row = wn + nt * 16 + lane16;
                int kc = (kk * 4 + quad) ^ (row & 7);
                bb[nt] = *(const bf16x8*)&Bs[row * 64 + kc * 8];
            }
#pragma unroll
            for (int mt = 0; mt < 2; mt++)
#pragma unroll
                for (int nt = 0; nt < 2; nt++)
                    acc[mt][nt] = __builtin_amdgcn_mfma_f32_16x16x32_bf16(a[mt], bb[nt], acc[mt][nt], 0, 0, 0);
        }
        __syncthreads();
    }

#pragma unroll
    for (int mt = 0; mt < 2; mt++) {
#pragma unroll
        for (int nt = 0; nt < 2; nt++) {
            int n = n0 + wn + nt * 16 + lane16;
#pragma unroll
            for (int rr = 0; rr < 4; rr++) {
                int m = m0 + wm + mt * 16 + quad * 4 + rr;
                if (m < M) Hout[(size_t)m * FF + n] = f2bf(acc[mt][nt][rr]);
            }
        }
    }
}

// ---------------------------------------------------------------------------
// Row sums over packed buckets -> dinv. One wave per row, 4 rows/block.
// ---------------------------------------------------------------------------
__global__ __launch_bounds__(256) void rowsum_dinv(const unsigned int* __restrict__ bucket,
                                                   const int* __restrict__ counts,
                                                   float* __restrict__ dinv) {
    int wave = threadIdx.x >> 6, lane = threadIdx.x & 63;
    int r = blockIdx.x * 4 + wave;
    int s = r * CAP;
    int e = s + min(counts[r], CAP);
    float sum = 0.0f;
    for (int i = s + lane; i < e; i += 64)
        sum += __uint_as_float(bucket[i] & 0xFFFF0000u);
#pragma unroll
    for (int off = 32; off > 0; off >>= 1) sum += __shfl_xor(sum, off);
    if (lane == 0) dinv[r] = (sum > 0.0f) ? rsqrtf(sum) : 0.0f;
}

// ---------------------------------------------------------------------------
// SpMM gather over packed buckets:
//   feat[r,:] = relu( dinv[r] * sum_e (w_e*dinv[c_e]) * H[c_e,:] + bias )
// One WAVE per row; lane covers 8 features (16B dwordx4 -> full 1KB H row per
// wave-load). 4 edges prefetched per single uint4 load. dinv[c] wave-uniform
// from a 24KB cache-resident table.
// Verified at its floor (r3/r4/r5 attacks all regressed): ~89% L2 hit,
// ~43 GB/s/CU == outstanding-miss-limited; pipelining, column-quarter and
// feature-half partitioning each made it worse.
// ---------------------------------------------------------------------------
__device__ __forceinline__ void accum8(float* acc, uint4 h, float v) {
    unsigned int d[4] = {h.x, h.y, h.z, h.w};
#pragma unroll
    for (int k = 0; k < 4; k++) {
        float lo = __uint_as_float(d[k] << 16);
        float hi = __uint_as_float(d[k] & 0xFFFF0000u);
        acc[2 * k]     = fmaf(v, lo, acc[2 * k]);
        acc[2 * k + 1] = fmaf(v, hi, acc[2 * k + 1]);
    }
}

__global__ __launch_bounds__(256) void spmm_bias_relu(const unsigned short* __restrict__ H,
                                                      const int* __restrict__ counts,
                                                      const unsigned int* __restrict__ bucket,
                                                      const float* __restrict__ dinv,
                                                      const float* __restrict__ bias,
                                                      unsigned short* __restrict__ featOut) {
    int wave = threadIdx.x >> 6, lane = threadIdx.x & 63;
    int r = blockIdx.x * 4 + wave;
    int s = r * CAP;
    int e = s + min(counts[r], CAP);
    int f0 = lane * 8;
    const unsigned short* Hf = H + f0;
    float acc[8] = {0, 0, 0, 0, 0, 0, 0, 0};

    int i = s;
    uint4 pk;
    bool have = (i + 4 <= e);
    if (have) pk = *(const uint4*)&bucket[i];
    while (have) {
        unsigned int q0 = pk.x, q1 = pk.y, q2 = pk.z, q3 = pk.w;
        uint4 a0 = *(const uint4*)(Hf + (size_t)(q0 & 0xFFFF) * FF);
        uint4 a1 = *(const uint4*)(Hf + (size_t)(q1 & 0xFFFF) * FF);
        uint4 a2 = *(const uint4*)(Hf + (size_t)(q2 & 0xFFFF) * FF);
        uint4 a3 = *(const uint4*)(Hf + (size_t)(q3 & 0xFFFF) * FF);
        float v0 = __uint_as_float(q0 & 0xFFFF0000u) * dinv[q0 & 0xFFFF];
        float v1 = __uint_as_float(q1 & 0xFFFF0000u) * dinv[q1 & 0xFFFF];
        float v2 = __uint_as_float(q2 & 0xFFFF0000u) * dinv[q2 & 0xFFFF];
        float v3 = __uint_as_float(q3 & 0xFFFF0000u) * dinv[q3 & 0xFFFF];
        i += 4;
        have = (i + 4 <= e);
        if (have) pk = *(const uint4*)&bucket[i];
        accum8(acc, a0, v0);
        accum8(acc, a1, v1);
        accum8(acc, a2, v2);
        accum8(acc, a3, v3);
    }
    for (; i < e; i++) {
        unsigned int q = bucket[i];
        uint4 a = *(const uint4*)(Hf + (size_t)(q & 0xFFFF) * FF);
        accum8(acc, a, __uint_as_float(q & 0xFFFF0000u) * dinv[q & 0xFFFF]);
    }

    float dr = dinv[r];
    float4 b0 = *(const float4*)(bias + f0);
    float4 b1 = *(const float4*)(bias + f0 + 4);
    float bb[8] = {b0.x, b0.y, b0.z, b0.w, b1.x, b1.y, b1.z, b1.w};
    unsigned int o[4];
#pragma unroll
    for (int k = 0; k < 4; k++) {
        float v0 = fmaxf(fmaf(acc[2 * k], dr, bb[2 * k]), 0.0f);
        float v1 = fmaxf(fmaf(acc[2 * k + 1], dr, bb[2 * k + 1]), 0.0f);
        o[k] = (unsigned int)f2bf(v0) | ((unsigned int)f2bf(v1) << 16);
    }
    uint4 ov; ov.x = o[0]; ov.y = o[1]; ov.z = o[2]; ov.w = o[3];
    *(uint4*)(featOut + (size_t)r * FF + f0) = ov;
}

// ---------------------------------------------------------------------------
// MFMA GEMM over stacked transposed weights Bt[n][k]. 64x64 tile, BK=64,
// 256 threads = 4 waves (2x2 of 32x32), XOR-swizzled LDS.
// MODE 1: all cols -> out += leaky_relu(v + fbias[n]), grid.y = 8
// MODE 2: n0<512 -> out += leaky_relu(v + fbias[n]); n0>=512 -> H store at
//         n-512, grid.y = 16 (Bt = [fW_i^T ; gW_{i+1}^T], same input feat)
// ---------------------------------------------------------------------------
template <int MODE>
__global__ __launch_bounds__(256) void gemm_bf16(const unsigned short* __restrict__ A,
                                                 const unsigned short* __restrict__ Bt,
                                                 const float* __restrict__ fbias,
                                                 unsigned short* __restrict__ Hout,
                                                 float* __restrict__ out,
                                                 int M) {
    __shared__ short As[64 * 64];
    __shared__ short Bs[64 * 64];
    int tid = threadIdx.x;
    int wave = tid >> 6;
    int lane = tid & 63;
    int lane16 = lane & 15;
    int quad = lane >> 4;
    int m0 = blockIdx.x * 64;
    int n0 = blockIdx.y * 64;
    int wm = (wave >> 1) * 32;
    int wn = (wave & 1) * 32;

    f32x4 acc[2][2] = {};

    for (int k0 = 0; k0 < FF; k0 += 64) {
#pragma unroll
        for (int s = 0; s < 2; s++) {
            int c = wave * 128 + s * 64 + lane;
            int row = c >> 3;
            int kc = (c & 7) ^ (row & 7);
            int ar = m0 + row; if (ar >= M) ar = M - 1;
            gload16((const short*)A + (size_t)ar * FF + k0 + kc * 8,
                    &As[(wave * 128 + s * 64) * 8]);
            gload16((const short*)Bt + (size_t)(n0 + row) * FF + k0 + kc * 8,
                    &Bs[(wave * 128 + s * 64) * 8]);
        }
        __syncthreads();
#pragma unroll
        for (int kk = 0; kk < 2; kk++) {
            bf16x8 a[2], bb[2];
#pragma unroll
            for (int mt = 0; mt < 2; mt++) {
                int row = wm + mt * 16 + lane16;
                int kc = (kk * 4 + quad) ^ (row & 7);
                a[mt] = *(const bf16x8*)&As[row * 64 + kc * 8];
            }
#pragma unroll
            for (int nt = 0; nt < 2; nt++) {
                int row = wn + nt * 16 + lane16;
                int kc = (kk * 4 + quad) ^ (row & 7);
                bb[nt] = *(const bf16x8*)&Bs[row * 64 + kc * 8];
            }
#pragma unroll
            for (int mt = 0; mt < 2; mt++)
#pragma unroll
                for (int nt = 0; nt < 2; nt++)
                    acc[mt][nt] = __builtin_amdgcn_mfma_f32_16x16x32_bf16(a[mt], bb[nt], acc[mt][nt], 0, 0, 0);
        }
        __syncthreads();
    }

    bool isFc = (MODE == 1) || (MODE == 2 && n0 < FF);
#pragma unroll
    for (int mt = 0; mt < 2; mt++) {
#pragma unroll
        for (int nt = 0; nt < 2; nt++) {
            int n = n0 + wn + nt * 16 + lane16;
            float bv = isFc ? fbias[n] : 0.0f;
#pragma unroll
            for (int rr = 0; rr < 4; rr++) {
                int m = m0 + wm + mt * 16 + quad * 4 + rr;
                if (m < M) {
                    float v = acc[mt][nt][rr];
                    if (isFc) {
                        v += bv;
                        v = (v > 0.0f) ? v : 0.01f * v;
                        out[(size_t)m * FF + n] += v;
                    } else {
                        Hout[(size_t)m * FF + (n - FF)] = f2bf(v);
                    }
                }
            }
        }
    }
}

// ---------------------------------------------------------------------------
extern "C" void kernel_launch(void* const* d_in, const int* in_sizes, int n_in,
                              void* d_out, int out_size, void* d_ws, size_t ws_size,
                              hipStream_t stream) {
    const float* xa      = (const float*)d_in[0];
    const float* xv      = (const float*)d_in[1];
    const float* xt      = (const float*)d_in[2];
    const float* ew      = (const float*)d_in[3];
    const float* gcn_W   = (const float*)d_in[4];
    const float* gcn_b   = (const float*)d_in[5];
    const float* fc_W    = (const float*)d_in[6];
    const float* fc_b    = (const float*)d_in[7];
    const int*   eidx    = (const int*)d_in[8];
    const int E = in_sizes[8] / 2;
    const int* esrc = eidx;
    const int* edst = eidx + E;

    float* out = (float*)d_out;

    // workspace layout (64B aligned blocks)
    char* w = (char*)d_ws;
    int*          counts = (int*)         (w + 0);          // 24,000 (pad 24,064)
    float*        dinv   = (float*)       (w + 24064);      // 24,000 (pad 48,128)
    unsigned int* bucket = (unsigned int*)(w + 48128);      // 6000*128*4 = 3,072,000
    unsigned short* feat = (unsigned short*)(w + 3120128);  // 6,144,000
    unsigned short* H    = (unsigned short*)(w + 9264128);  // 6,144,000
    unsigned short* Wt   = (unsigned short*)(w + 15408128); // 2,097,152
    int*          pir    = (int*)         (w + 17505280);   // E*4 = 1,600,000

    hipMemsetAsync(counts, 0, 24000, stream);

    const int eblocks = (E + 255) / 256;
    prep<<<3256 + eblocks, 256, 0, stream>>>(xa, xv, xt, feat, out,
                                             gcn_W, fc_W, Wt, esrc, counts, pir, E);

    const int gxm = (NN + 63) / 64;   // 94
    const int ngemm0 = gxm * 8;       // 752
    // Wt slots: 0=gW0^T, 1=fW0^T, 2=gW1^T, 3=fW1^T (slots 1,2 contiguous)
    // merged: scatter (first, starts early) || H0 = feat0 @ gW0
    gemm0_scatter<<<eblocks + ngemm0, 256, 0, stream>>>(feat, Wt, H, NN, gxm, eblocks,
                                                        esrc, edst, ew, pir, bucket, E);
    rowsum_dinv<<<NN / 4, 256, 0, stream>>>(bucket, counts, dinv);

    // feat1 = relu(gcn@H0 + gb0)
    spmm_bias_relu<<<NN / 4, 256, 0, stream>>>(H, counts, bucket, dinv, gcn_b, feat);
    // out += leaky(feat1@fW0 + fb0)  AND  H1 = feat1 @ gW1   (fused)
    gemm_bf16<2><<<dim3(gxm, 16), 256, 0, stream>>>(feat, Wt + (size_t)FF * FF, fc_b, H, out, NN);
    // feat2 = relu(gcn@H1 + gb1)
    spmm_bias_relu<<<NN / 4, 256, 0, stream>>>(H, counts, bucket, dinv, gcn_b + FF, feat);
    // out += leaky(feat2@fW1 + fb1)
    gemm_bf16<1><<<dim3(gxm, 8), 256, 0, stream>>>(feat, Wt + (size_t)3 * FF * FF, fc_b + FF, nullptr, out, NN);
}